// Round 5
// baseline (230.525 us; speedup 1.0000x reference)
//
#include <hip/hip_runtime.h>
#include <hip/hip_bf16.h>
#include <cstdint>
#include <cstddef>

// Problem constants
#define BB   128   // batch
#define SS   128   // set size
#define GG   2000  // genes (K of input proj)
#define NHID 256   // n_hidden
#define NHEAD 4
#define HDIM 64
#define NLAT 64
#define KPAD 2048  // padded K for input proj (2 x 1024 split-K)

typedef __attribute__((ext_vector_type(4))) float f32x4;
typedef __attribute__((ext_vector_type(8))) short short8;
typedef __attribute__((ext_vector_type(4))) short bfs4;
typedef __attribute__((ext_vector_type(8))) __bf16 bf8_t;

static __device__ __forceinline__ bf8_t as_bf8(short8 s){
  union { short8 s; bf8_t b; } u; u.s = s; return u.b;
}

static __device__ __forceinline__ unsigned short f2bf(float f){
  union { float f; unsigned u; } x; x.f = f;
  unsigned r = x.u + 0x7fffu + ((x.u >> 16) & 1u);
  return (unsigned short)(r >> 16);
}

#define GLOAD_LDS16(g, l) __builtin_amdgcn_global_load_lds( \
    (const __attribute__((address_space(1))) unsigned int*)(g), \
    (__attribute__((address_space(3))) unsigned int*)(l), 16, 0, 0)

// ---------------------------------------------------------------------------
// x_set (16384 x 2000 f32) -> Xb (16384 x 2048 bf16, zero-padded)
// ---------------------------------------------------------------------------
__global__ __launch_bounds__(256) void k_x2bf(
    const float* __restrict__ X, unsigned short* __restrict__ Xb)
{
  const int gid = blockIdx.x * 256 + threadIdx.x;   // short8 unit
  const int row = gid >> 8;                          // 256 units per row
  const int c8  = gid & 255;
  const int k0  = c8 << 3;
  short8 v;
  if (k0 < GG) {   // GG = 2000 = 250*8, so full or zero
    f32x4 a0 = *(const f32x4*)(X + (size_t)row * GG + k0);
    f32x4 a1 = *(const f32x4*)(X + (size_t)row * GG + k0 + 4);
    v[0]=(short)f2bf(a0.x); v[1]=(short)f2bf(a0.y); v[2]=(short)f2bf(a0.z); v[3]=(short)f2bf(a0.w);
    v[4]=(short)f2bf(a1.x); v[5]=(short)f2bf(a1.y); v[6]=(short)f2bf(a1.z); v[7]=(short)f2bf(a1.w);
  } else {
#pragma unroll
    for (int t = 0; t < 8; ++t) v[t] = 0;
  }
  *(short8*)(Xb + (size_t)row * KPAD + k0) = v;
}

// ---------------------------------------------------------------------------
// Transpose + convert + zero-pad: W (K x N, f32) -> Wt (N x Kpad, bf16)
// ---------------------------------------------------------------------------
__global__ __launch_bounds__(256) void k_transconv(
    const float* __restrict__ W, unsigned short* __restrict__ Wt,
    int K, int N, int Kpad)
{
  int idx = blockIdx.x * 256 + threadIdx.x;
  if (idx >= N * Kpad) return;
  int n = idx / Kpad, k = idx - n * Kpad;
  float v = (k < K) ? W[(size_t)k * N + n] : 0.f;
  Wt[idx] = f2bf(v);
}

// ---------------------------------------------------------------------------
// adj (B x S x S i32) -> bitmask (B*S*2 u64): one wave packs 64 ints.
// ---------------------------------------------------------------------------
__global__ __launch_bounds__(256) void k_adjpack(
    const int* __restrict__ adj, unsigned long long* __restrict__ abits)
{
  const int wid  = blockIdx.x * 4 + (threadIdx.x >> 6);
  const int lane = threadIdx.x & 63;
  int v = adj[(size_t)wid * 64 + lane];
  unsigned long long m = __ballot(v != 0);
  if (lane == 0) abits[wid] = m;
}

// ---------------------------------------------------------------------------
// Input GEMM: Out[z][M][256] = Xb[:, z*1024:(z+1)*1024] @ Wt^T
//   BM=128, BN=256 (full), BK=32; 512 thr = 8 waves (2x4 of 64x64).
//   A read ONCE per tile (no N-split). Split-K via blockIdx.y.
// ---------------------------------------------------------------------------
__global__ __launch_bounds__(512, 1) void k_gemm_in(
    const unsigned short* __restrict__ A,   // [M][KPAD] bf16
    const unsigned short* __restrict__ Bt,  // [256][KPAD] bf16
    float* __restrict__ Out)                // [2][M][256] f32
{
  __shared__ __align__(16) unsigned short Ab[2][8][64][8];    // 16 KB
  __shared__ __align__(16) unsigned short Bb[2][16][64][8];   // 32 KB
  const int tid = threadIdx.x, l = tid & 63, w = tid >> 6;
  const int wr = w >> 2, wc = w & 3;
  const int m0 = blockIdx.x * 128;
  const int kbase0 = blockIdx.y * 1024;
  const int nsteps = 32;

  const unsigned short* aB = A  + (size_t)(m0 + (l & 15)) * KPAD + kbase0 + (l >> 4) * 8;
  const unsigned short* bB = Bt + (size_t)(l & 15) * KPAD + kbase0 + (l >> 4) * 8;

  f32x4 acc[4][4];
#pragma unroll
  for (int i = 0; i < 4; ++i)
#pragma unroll
    for (int j = 0; j < 4; ++j) acc[i][j] = (f32x4)(0.f);

  auto stage = [&](int buf, int koff) {
#pragma unroll
    for (int q = 0; q < 3; ++q) {
      const int tile = w * 3 + q;                 // 0..23, wave-uniform
      if (tile < 8) {
        GLOAD_LDS16(aB + (size_t)(16 * tile) * KPAD + koff, &Ab[buf][tile][0][0]);
      } else {
        GLOAD_LDS16(bB + (size_t)(16 * (tile - 8)) * KPAD + koff, &Bb[buf][tile - 8][0][0]);
      }
    }
  };

  stage(0, 0);
  __syncthreads();

  for (int s = 0; s < nsteps; ++s) {
    const int cur = s & 1;
    if (s + 1 < nsteps) stage(cur ^ 1, (s + 1) * 32);
    short8 af[4], bfv[4];
#pragma unroll
    for (int i = 0; i < 4; ++i) af[i]  = *(const short8*)&Ab[cur][4 * wr + i][l][0];
#pragma unroll
    for (int j = 0; j < 4; ++j) bfv[j] = *(const short8*)&Bb[cur][4 * wc + j][l][0];
#pragma unroll
    for (int i = 0; i < 4; ++i)
#pragma unroll
      for (int j = 0; j < 4; ++j)
        acc[i][j] = __builtin_amdgcn_mfma_f32_16x16x32_bf16(
            as_bf8(af[i]), as_bf8(bfv[j]), acc[i][j], 0, 0, 0);
    __syncthreads();
  }

  float* outp = Out + (size_t)blockIdx.y * ((size_t)BB * SS * NHID);
  const int orow = m0 + (wr << 6) + ((l >> 4) << 2);
  const int ocol = (wc << 6) + (l & 15);
#pragma unroll
  for (int i = 0; i < 4; ++i)
#pragma unroll
    for (int j = 0; j < 4; ++j) {
      const int row = orow + i * 16, col = ocol + j * 16;
#pragma unroll
      for (int r = 0; r < 4; ++r)
        outp[(size_t)(row + r) * NHID + col] = acc[i][j][r];
    }
}

// ---------------------------------------------------------------------------
// hp GEMM: hpT[b][d(256)][j(128)] bf16 = (h @ Wg)^T per batch.
//   BM=128 (one batch), BN=128, BK=32; 256 thr = 4 waves (2x2).
// ---------------------------------------------------------------------------
__global__ __launch_bounds__(256, 2) void k_gemm_hp(
    const unsigned short* __restrict__ A,   // [M][256] bf16 (h)
    const unsigned short* __restrict__ Bt,  // [256][256] bf16 (Wg^T)
    unsigned short* __restrict__ hpT)       // [BB][256][128] bf16
{
  __shared__ __align__(16) unsigned short Ab[2][8][64][8];
  __shared__ __align__(16) unsigned short Bb[2][8][64][8];
  const int tid = threadIdx.x, l = tid & 63, w = tid >> 6;
  const int wr = w >> 1, wc = w & 1;
  const int m0 = blockIdx.x * 128, n0 = blockIdx.y * 128;

  const int rA = l & 15;
  const unsigned short* aB = A  + (size_t)(m0 + rA) * NHID + (l >> 4) * 8;
  const unsigned short* bB = Bt + (size_t)(n0 + rA) * NHID + (l >> 4) * 8;

  f32x4 acc[4][4];
#pragma unroll
  for (int i = 0; i < 4; ++i)
#pragma unroll
    for (int j = 0; j < 4; ++j) acc[i][j] = (f32x4)(0.f);

  auto stage = [&](int buf, int koff) {
#pragma unroll
    for (int t = 0; t < 2; ++t) {
      const int ia = 2 * w + t;
      GLOAD_LDS16(aB + (size_t)(16 * ia) * NHID + koff, &Ab[buf][ia][0][0]);
      GLOAD_LDS16(bB + (size_t)(16 * ia) * NHID + koff, &Bb[buf][ia][0][0]);
    }
  };

  stage(0, 0);
  __syncthreads();

  for (int s = 0; s < 8; ++s) {
    const int cur = s & 1;
    if (s + 1 < 8) stage(cur ^ 1, (s + 1) * 32);
    short8 af[4], bfv[4];
#pragma unroll
    for (int i = 0; i < 4; ++i) af[i]  = *(const short8*)&Ab[cur][4 * wr + i][l][0];
#pragma unroll
    for (int j = 0; j < 4; ++j) bfv[j] = *(const short8*)&Bb[cur][4 * wc + j][l][0];
#pragma unroll
    for (int i = 0; i < 4; ++i)
#pragma unroll
      for (int j = 0; j < 4; ++j)
        acc[i][j] = __builtin_amdgcn_mfma_f32_16x16x32_bf16(
            as_bf8(af[i]), as_bf8(bfv[j]), acc[i][j], 0, 0, 0);
    __syncthreads();
  }

  // transposed store: hpT[b][col][i], b = m0>>7 (block-constant), i = row&127
  const int bidx = m0 >> 7;
  const int i0 = (wr << 6) + ((l >> 4) << 2);      // row within batch
  const int ocol = n0 + (wc << 6) + (l & 15);
  unsigned short* hb = hpT + (size_t)bidx * NHID * SS;
#pragma unroll
  for (int i = 0; i < 4; ++i)
#pragma unroll
    for (int j = 0; j < 4; ++j) {
      const int col = ocol + j * 16;
      bfs4 o;
#pragma unroll
      for (int r = 0; r < 4; ++r) o[r] = (short)f2bf(acc[i][j][r]);
      *(bfs4*)&hb[(size_t)col * SS + i0 + i * 16] = o;
    }
}

// ---------------------------------------------------------------------------
// Fused: x = X0 (+X1) (+bias) -> LayerNorm -> GELU -> bf16 h (+f32 h)
//        (+ scores c1 = h@u1, c2 = h@u2 when u != null)
// ---------------------------------------------------------------------------
__global__ __launch_bounds__(256) void k_ln_fuse(
    const float* __restrict__ X0, const float* __restrict__ X1,
    const float* __restrict__ bias, const float* __restrict__ g,
    const float* __restrict__ b, unsigned short* __restrict__ out_bf,
    float* __restrict__ out_f32, const float* __restrict__ u,
    float* __restrict__ c1, float* __restrict__ c2)
{
  const int tid = threadIdx.x, l = tid & 63, w = tid >> 6;
  const f32x4 gg = *(const f32x4*)(g + l * 4);
  const f32x4 bb = *(const f32x4*)(b + l * 4);
  f32x4 bias4 = (f32x4)(0.f);
  if (bias) bias4 = *(const f32x4*)(bias + l * 4);
  f32x4 u1v[4], u2v[4];
  if (u) {
#pragma unroll
    for (int t = 0; t < 4; ++t) {
      u1v[t] = *(const f32x4*)(u + (size_t)(4 * l + t) * 4);
      u2v[t] = *(const f32x4*)(u + 1024 + (size_t)(4 * l + t) * 4);
    }
  }
  for (int it = 0; it < 4; ++it) {
    const int row = blockIdx.x * 16 + w * 4 + it;
    f32x4 x = *(const f32x4*)(X0 + (size_t)row * NHID + l * 4);
    if (X1) {
      f32x4 x1 = *(const f32x4*)(X1 + (size_t)row * NHID + l * 4);
      x.x += x1.x; x.y += x1.y; x.z += x1.z; x.w += x1.w;
    }
    x.x += bias4.x; x.y += bias4.y; x.z += bias4.z; x.w += bias4.w;
    float s  = x.x + x.y + x.z + x.w;
    float sq = x.x * x.x + x.y * x.y + x.z * x.z + x.w * x.w;
#pragma unroll
    for (int m = 1; m < 64; m <<= 1) { s += __shfl_xor(s, m); sq += __shfl_xor(sq, m); }
    const float mu   = s * (1.f / 256.f);
    const float var  = sq * (1.f / 256.f) - mu * mu;
    const float rstd = rsqrtf(var + 1e-5f);
    float y[4];
#pragma unroll
    for (int t = 0; t < 4; ++t) {
      float yy = (x[t] - mu) * rstd * gg[t] + bb[t];
      y[t] = 0.5f * yy * (1.f + erff(yy * 0.70710678118654752f));
    }
    if (out_bf) {
      bfs4 o;
#pragma unroll
      for (int t = 0; t < 4; ++t) o[t] = (short)f2bf(y[t]);
      *(bfs4*)(out_bf + (size_t)row * NHID + l * 4) = o;
    }
    if (out_f32) {
      f32x4 o; o.x = y[0]; o.y = y[1]; o.z = y[2]; o.w = y[3];
      *(f32x4*)(out_f32 + (size_t)row * NHID + l * 4) = o;
    }
    if (u) {
      float d1[4] = {0.f,0.f,0.f,0.f}, d2[4] = {0.f,0.f,0.f,0.f};
#pragma unroll
      for (int t = 0; t < 4; ++t)
#pragma unroll
        for (int h = 0; h < 4; ++h) {
          d1[h] += y[t] * u1v[t][h];
          d2[h] += y[t] * u2v[t][h];
        }
#pragma unroll
      for (int h = 0; h < 4; ++h) {
#pragma unroll
        for (int m = 1; m < 64; m <<= 1) {
          d1[h] += __shfl_xor(d1[h], m);
          d2[h] += __shfl_xor(d2[h], m);
        }
      }
      if (l == 0) {
#pragma unroll
        for (int h = 0; h < 4; ++h) {
          c1[(size_t)row * 4 + h] = d1[h];
          c2[(size_t)row * 4 + h] = d2[h];
        }
      }
    }
  }
}

// ---------------------------------------------------------------------------
// Fold a_src/a_dst/a_edge into u matrices (both layers; blockIdx.x = layer)
// ---------------------------------------------------------------------------
__global__ __launch_bounds__(256, 1) void k_proj(
    const float* __restrict__ Wg, const float* __restrict__ We,
    const float* __restrict__ asrc, const float* __restrict__ adst,
    const float* __restrict__ aedge, float* __restrict__ u)
{
  const int lyr = blockIdx.x;
  const int k = threadIdx.x;
  const float* Wgl = Wg + (size_t)lyr * NHID * NHID;
  const float* Wel = We + (size_t)lyr * NHID * NHID;
  float* u1 = u + (size_t)lyr * 2048;
  float* u2 = u1 + 1024;
#pragma unroll
  for (int h = 0; h < 4; ++h) {
    float ss = 0.f, sd = 0.f, se = 0.f;
    const float* wg  = Wgl + k * NHID + h * 64;
    const float* we  = Wel + k * NHID + h * 64;
    const float* pas = asrc + lyr * NHEAD * HDIM + h * 64;
    const float* pad_ = adst + lyr * NHEAD * HDIM + h * 64;
    const float* pae = aedge + lyr * NHEAD * HDIM + h * 64;
#pragma unroll 4
    for (int d = 0; d < 64; ++d) {
      ss += wg[d] * pas[d];
      sd += wg[d] * pad_[d];
      se += we[d] * pae[d];
    }
    u1[k * 4 + h] = ss + se;
    u2[k * 4 + h] = sd - se;
  }
}

// ---------------------------------------------------------------------------
// GAT attention v3: block per (head, b). Lane-per-row softmax, bitmask adj,
// Vb staged from transposed hp via global_load_lds, PV via MFMA.
// ---------------------------------------------------------------------------
__global__ __launch_bounds__(256) void k_attn2(
    const unsigned short* __restrict__ hpT, const float* __restrict__ c1,
    const float* __restrict__ c2, const unsigned long long* __restrict__ abits,
    float* __restrict__ out)
{
  __shared__ __align__(16) unsigned short Pb[4][8][64][8];   // 32 KB A-frags
  __shared__ __align__(16) unsigned short Vb[4][4][64][8];   // 16 KB B-frags
  __shared__ float s1[128], s2[128];
  __shared__ float mbuf[2][128], sbuf[2][128], invsum[128];
  const int head = blockIdx.x, b = blockIdx.y;
  const int tid = threadIdx.x, w = tid >> 6, l = tid & 63;

  if (tid < 128) {
    const int m = b * SS + tid;
    s1[tid] = c1[m * 4 + head];
    s2[tid] = c2[m * 4 + head];
  }
  // stage hpT slice -> Vb B-fragment layout (async, per-lane global addr)
  {
    const unsigned short* hb = hpT + ((size_t)b * NHID + head * 64) * SS;
#pragma unroll
    for (int q = 0; q < 4; ++q) {
      const int tile = w * 4 + q;                  // 0..15, wave-uniform
      const int kstep = tile >> 2, nt = tile & 3;
      const unsigned short* src =
          hb + (size_t)(nt * 16 + (l & 15)) * SS + kstep * 32 + (l >> 4) * 8;
      GLOAD_LDS16(src, &Vb[kstep][nt][0][0]);
    }
  }
  __syncthreads();

  const int i = tid & 127, half = tid >> 7;
  const float s1v = s1[i];
  const unsigned long long bits = abits[((size_t)b * SS + i) * 2 + half];

  // pass 1: row-half max (serial per thread, 4 independent chains)
  float ma[4] = {-3.0e38f, -3.0e38f, -3.0e38f, -3.0e38f};
#pragma unroll
  for (int jl = 0; jl < 64; ++jl) {
    float x  = s1v + s2[half * 64 + jl];
    float lk = fmaxf(x, 0.2f * x);                  // LeakyReLU(0.2)
    float xm = ((bits >> jl) & 1ull) ? lk : -3.0e38f;
    ma[jl & 3] = fmaxf(ma[jl & 3], xm);
  }
  mbuf[half][i] = fmaxf(fmaxf(ma[0], ma[1]), fmaxf(ma[2], ma[3]));
  __syncthreads();
  const float mrow = fmaxf(mbuf[0][i], mbuf[1][i]);

  // pass 2: exp, sum, write P fragments (unnormalized, bf16)
  float sa[4] = {0.f, 0.f, 0.f, 0.f};
#pragma unroll
  for (int grp = 0; grp < 8; ++grp) {
    short8 pv;
#pragma unroll
    for (int e = 0; e < 8; ++e) {
      const int jl = grp * 8 + e;
      float x  = s1v + s2[half * 64 + jl];
      float lk = fmaxf(x, 0.2f * x);
      float xm = ((bits >> jl) & 1ull) ? lk : -3.0e38f;
      float p  = exp2f((xm - mrow) * 1.4426950408889634f);
      sa[e & 3] += p;
      pv[e] = (short)f2bf(p);
    }
    const int j = half * 64 + grp * 8;
    const int kstep = j >> 5, g = (j >> 3) & 3;
    *(short8*)&Pb[kstep][i >> 4][(g << 4) | (i & 15)][0] = pv;
  }
  sbuf[half][i] = (sa[0] + sa[1]) + (sa[2] + sa[3]);
  __syncthreads();
  if (tid < 128) invsum[tid] = 1.f / (sbuf[0][tid] + sbuf[1][tid]);
  __syncthreads();

  // phase 3: PV via MFMA. wave w owns output rows [w*32, w*32+32)
  f32x4 acc[2][4];
#pragma unroll
  for (int ii = 0; ii < 2; ++ii)
#pragma unroll
    for (int nt = 0; nt < 4; ++nt) acc[ii][nt] = (f32x4)(0.f);
#pragma unroll
  for (int kstep = 0; kstep < 4; ++kstep) {
    short8 bv[4];
#pragma unroll
    for (int nt = 0; nt < 4; ++nt) bv[nt] = *(const short8*)&Vb[kstep][nt][l][0];
#pragma unroll
    for (int ii = 0; ii < 2; ++ii) {
      short8 af = *(const short8*)&Pb[kstep][2 * w + ii][l][0];
#pragma unroll
      for (int nt = 0; nt < 4; ++nt)
        acc[ii][nt] = __builtin_amdgcn_mfma_f32_16x16x32_bf16(
            as_bf8(af), as_bf8(bv[nt]), acc[ii][nt], 0, 0, 0);
    }
  }

  // epilogue: normalize by 1/sum and store f32
  float* ob = out + (size_t)(b * SS) * NHID + head * 64;
#pragma unroll
  for (int ii = 0; ii < 2; ++ii) {
    const int it = 2 * w + ii;
#pragma unroll
    for (int r = 0; r < 4; ++r) {
      const int row = it * 16 + (l >> 4) * 4 + r;
      const float inv = invsum[row];
#pragma unroll
      for (int nt = 0; nt < 4; ++nt)
        ob[(size_t)row * NHID + nt * 16 + (l & 15)] = acc[ii][nt][r] * inv;
    }
  }
}

// ---------------------------------------------------------------------------
// Final projection: Z[16384 x 64] = h @ Wz + bz.  64 rows per block.
// ---------------------------------------------------------------------------
__global__ __launch_bounds__(256, 1) void k_zgemm(
    const float* __restrict__ hmat, const float* __restrict__ Wz,
    const float* __restrict__ bz, float* __restrict__ Z)
{
  __shared__ __align__(16) float hrows[64 * 256];
  const int tid = threadIdx.x, w = tid >> 6, l = tid & 63;
  const int r0 = blockIdx.x * 64;
  const f32x4* src = (const f32x4*)(hmat + (size_t)r0 * NHID);
#pragma unroll
  for (int rep = 0; rep < 16; ++rep)
    ((f32x4*)hrows)[rep * 256 + tid] = src[rep * 256 + tid];
  __syncthreads();
  const float bzv = bz[l];
  const int rbase = w * 16;
#pragma unroll
  for (int pass = 0; pass < 4; ++pass) {
    float acc0 = 0.f, acc1 = 0.f, acc2 = 0.f, acc3 = 0.f;
    const float* h0 = &hrows[(rbase + pass * 4) * 256];
#pragma unroll 8
    for (int k = 0; k < 256; ++k) {
      float wv = Wz[k * 64 + l];
      acc0 += h0[k] * wv;
      acc1 += h0[256 + k] * wv;
      acc2 += h0[512 + k] * wv;
      acc3 += h0[768 + k] * wv;
    }
    float* zp = Z + (size_t)(r0 + rbase + pass * 4) * 64 + l;
    zp[0]   = acc0 + bzv;
    zp[64]  = acc1 + bzv;
    zp[128] = acc2 + bzv;
    zp[192] = acc3 + bzv;
  }
}

// ---------------------------------------------------------------------------
extern "C" void kernel_launch(void* const* d_in, const int* in_sizes, int n_in,
                              void* d_out, int out_size, void* d_ws, size_t ws_size,
                              hipStream_t stream)
{
  const float* x_set   = (const float*)d_in[0];
  const int*   adj     = (const int*)d_in[1];
  const float* W_in    = (const float*)d_in[2];
  const float* b_in    = (const float*)d_in[3];
  const float* ln_in_g = (const float*)d_in[4];
  const float* ln_in_b = (const float*)d_in[5];
  const float* Wg      = (const float*)d_in[6];
  const float* a_src   = (const float*)d_in[7];
  const float* a_dst   = (const float*)d_in[8];
  const float* a_edge  = (const float*)d_in[9];
  const float* We      = (const float*)d_in[10];
  const float* ln_g    = (const float*)d_in[11];
  const float* ln_b    = (const float*)d_in[12];
  const float* Wz      = (const float*)d_in[13];
  const float* bz      = (const float*)d_in[14];
  float* zout = (float*)d_out;

  const int M = BB * SS;   // 16384

  char* base = (char*)d_ws;
  size_t off = 0;
  auto alloc = [&](size_t bytes) { char* p = base + off; off += (bytes + 255) & ~(size_t)255; return p; };
  unsigned short* Xb    = (unsigned short*)alloc((size_t)M * KPAD * 2);      // 67.1 MB
  float*          P     = (float*)alloc((size_t)M * NHID * 4 * 2);           // 33.6 MB (P0,P1)
  unsigned short* hbf   = (unsigned short*)alloc((size_t)M * NHID * 2);      // 8.4 MB
  unsigned short* wt_in = (unsigned short*)alloc((size_t)NHID * KPAD * 2);   // 1 MB
  unsigned short* wgt   = (unsigned short*)alloc((size_t)NHID * NHID * 2);   // 128 KB
  float*          u     = (float*)alloc(2 * 2048 * 4);
  float*          c1    = (float*)alloc((size_t)M * 4 * 4);
  float*          c2    = (float*)alloc((size_t)M * 4 * 4);
  unsigned long long* abits = (unsigned long long*)alloc((size_t)BB * SS * 2 * 8); // 256 KB
  // Xb region is dead after the input GEMM; reuse it for per-layer buffers.
  unsigned short* hpT = Xb;                        // hp^T bf16 (8.4 MB)
  float* bufA = (float*)Xb + (size_t)M * NHID;     // attn out f32 (16.8 MB)
  float* hfin = P;                                 // final h f32 (reuse P0)

  // 1) x_set -> bf16 padded
  k_x2bf<<<dim3((M * (KPAD / 8)) / 256), dim3(256), 0, stream>>>(x_set, Xb);
  // 2) W_in -> bf16 transposed+padded
  k_transconv<<<dim3((NHID * KPAD) / 256), dim3(256), 0, stream>>>(
      W_in, wt_in, GG, NHID, KPAD);
  // 3) fold attention vectors (both layers); pack adj bitmask
  k_proj<<<dim3(2), dim3(256), 0, stream>>>(Wg, We, a_src, a_dst, a_edge, u);
  k_adjpack<<<dim3(BB * SS * 2 / 4), dim3(256), 0, stream>>>(adj, abits);
  // 4) input proj GEMM, BN=256, split-K=2 -> P0,P1
  k_gemm_in<<<dim3(M / 128, 2), dim3(512), 0, stream>>>(Xb, wt_in, P);
  // 5) reduce + bias + LN + GELU -> hbf, + scores for layer 0
  k_ln_fuse<<<dim3(M / 16), dim3(256), 0, stream>>>(
      P, P + (size_t)M * NHID, b_in, ln_in_g, ln_in_b, hbf, nullptr,
      u, c1, c2);

  for (int l = 0; l < 2; ++l) {
    const float* Wgl = Wg + (size_t)l * NHID * NHID;
    // a) Wg[l] -> bf16 transposed
    k_transconv<<<dim3((NHID * NHID) / 256), dim3(256), 0, stream>>>(
        Wgl, wgt, NHID, NHID, NHID);
    // b) hp^T = (h @ Wg[l])^T -> hpT (bf16)
    k_gemm_hp<<<dim3(M / 128, 2), dim3(256), 0, stream>>>(hbf, wgt, hpT);
    // c) attention -> bufA
    k_attn2<<<dim3(NHEAD, BB), dim3(256), 0, stream>>>(
        hpT, c1, c2, abits, bufA);
    // d) LN + GELU (+ next-layer scores, or final f32 h)
    if (l == 0) {
      k_ln_fuse<<<dim3(M / 16), dim3(256), 0, stream>>>(
          bufA, nullptr, nullptr, ln_g, ln_b, hbf, nullptr,
          u + 2048, c1, c2);
    } else {
      k_ln_fuse<<<dim3(M / 16), dim3(256), 0, stream>>>(
          bufA, nullptr, nullptr, ln_g + NHID, ln_b + NHID, nullptr, hfin,
          nullptr, nullptr, nullptr);
    }
  }

  // 6) final projection
  k_zgemm<<<dim3(M / 64), dim3(256), 0, stream>>>(hfin, Wz, bz, zout);
}

// Round 6
// 202.201 us; speedup vs baseline: 1.1401x; 1.1401x over previous
//
#include <hip/hip_runtime.h>
#include <hip/hip_bf16.h>
#include <cstdint>
#include <cstddef>

// Problem constants
#define BB   128   // batch
#define SS   128   // set size
#define GG   2000  // genes (K of input proj)
#define NHID 256   // n_hidden
#define NHEAD 4
#define HDIM 64
#define NLAT 64
#define KPAD 2048  // padded K for W_in^T (bf16)
#define KSPLIT 1000 // K per split for input GEMM (2 x 1000, 8-aligned)

typedef __attribute__((ext_vector_type(4))) float f32x4;
typedef __attribute__((ext_vector_type(8))) short short8;
typedef __attribute__((ext_vector_type(4))) short bfs4;
typedef __attribute__((ext_vector_type(8))) __bf16 bf8_t;

static __device__ __forceinline__ bf8_t as_bf8(short8 s){
  union { short8 s; bf8_t b; } u; u.s = s; return u.b;
}

static __device__ __forceinline__ unsigned short f2bf(float f){
  union { float f; unsigned u; } x; x.f = f;
  unsigned r = x.u + 0x7fffu + ((x.u >> 16) & 1u);
  return (unsigned short)(r >> 16);
}

#define GLOAD_LDS16(g, l) __builtin_amdgcn_global_load_lds( \
    (const __attribute__((address_space(1))) unsigned int*)(g), \
    (__attribute__((address_space(3))) unsigned int*)(l), 16, 0, 0)

// ---------------------------------------------------------------------------
// Transpose + convert + zero-pad: W (K x N, f32) -> Wt (N x Kpad, bf16)
// ---------------------------------------------------------------------------
__global__ __launch_bounds__(256) void k_transconv(
    const float* __restrict__ W, unsigned short* __restrict__ Wt,
    int K, int N, int Kpad)
{
  int idx = blockIdx.x * 256 + threadIdx.x;
  if (idx >= N * Kpad) return;
  int n = idx / Kpad, k = idx - n * Kpad;
  float v = (k < K) ? W[(size_t)k * N + n] : 0.f;
  Wt[idx] = f2bf(v);
}

// ---------------------------------------------------------------------------
// adj (B x S x S i32) -> bitmask (B*S*2 u64): one wave packs 64 ints.
// ---------------------------------------------------------------------------
__global__ __launch_bounds__(256) void k_adjpack(
    const int* __restrict__ adj, unsigned long long* __restrict__ abits)
{
  const int wid  = blockIdx.x * 4 + (threadIdx.x >> 6);
  const int lane = threadIdx.x & 63;
  int v = adj[(size_t)wid * 64 + lane];
  unsigned long long m = __ballot(v != 0);
  if (lane == 0) abits[wid] = m;
}

// ---------------------------------------------------------------------------
// Input GEMM (fused f32->bf16 A conversion):
//   Out[z][M][256] = x_set[:, z*1000:(z+1)*1000] @ Wt^T
//   BM=64, BN=256 (full), BK=32; 256 thr = 4 waves, wave w = cols [64w,64w+64).
//   A: reg-staged from f32 (load early / convert+ds_write late, T14-lite).
//   B: global_load_lds 16B. Double-buffered. grid (M/64, 2) = 512 blocks.
// ---------------------------------------------------------------------------
__global__ __launch_bounds__(256, 2) void k_gemm_in(
    const float* __restrict__ X,            // [M][2000] f32
    const unsigned short* __restrict__ Bt,  // [256][KPAD] bf16
    float* __restrict__ Out)                // [2][M][256] f32
{
  __shared__ __align__(16) unsigned short Ab[2][4][64][8];    // 8 KB
  __shared__ __align__(16) unsigned short Bb[2][16][64][8];   // 32 KB
  const int tid = threadIdx.x, l = tid & 63, w = tid >> 6;
  const int m0 = blockIdx.x * 64;
  const int kbase = blockIdx.y * KSPLIT;
  const int nsteps = 32;                     // 32*32 = 1024 >= 1000 (tail zeroed)

  // A staging slot: this thread owns Ab[buf][w][l][:]
  //   row = (l&15) + 16*w,  k-group = (l>>4)*8
  const int akg8 = (l >> 4) * 8;
  const float* aP = X + (size_t)(m0 + (l & 15) + 16 * w) * GG + kbase + akg8;
  // B staging base: lane l covers B-row (l&15)+16*tile, k (l>>4)*8
  const unsigned short* bB = Bt + (size_t)(l & 15) * KPAD + kbase + akg8;

  f32x4 acc[4][4];
#pragma unroll
  for (int i = 0; i < 4; ++i)
#pragma unroll
    for (int j = 0; j < 4; ++j) acc[i][j] = (f32x4)(0.f);

  auto stage_b = [&](int buf, int koff) {
#pragma unroll
    for (int q = 0; q < 4; ++q) {
      const int tile = w * 4 + q;            // wave-uniform
      GLOAD_LDS16(bB + (size_t)(16 * tile) * KPAD + koff, &Bb[buf][tile][0][0]);
    }
  };
  auto load_a = [&](int koff, f32x4& a0, f32x4& a1) {
    if (koff + akg8 < KSPLIT) {              // 1000 % 8 == 0: full or none
      a0 = *(const f32x4*)(aP + koff);
      a1 = *(const f32x4*)(aP + koff + 4);
    } else {
      a0 = (f32x4)(0.f); a1 = (f32x4)(0.f);
    }
  };
  auto write_a = [&](int buf, const f32x4& a0, const f32x4& a1) {
    short8 v;
    v[0]=(short)f2bf(a0.x); v[1]=(short)f2bf(a0.y); v[2]=(short)f2bf(a0.z); v[3]=(short)f2bf(a0.w);
    v[4]=(short)f2bf(a1.x); v[5]=(short)f2bf(a1.y); v[6]=(short)f2bf(a1.z); v[7]=(short)f2bf(a1.w);
    *(short8*)&Ab[buf][w][l][0] = v;
  };

  {
    f32x4 a0, a1;
    stage_b(0, 0);
    load_a(0, a0, a1);
    write_a(0, a0, a1);
  }
  __syncthreads();

  for (int s = 0; s < nsteps; ++s) {
    const int cur = s & 1;
    f32x4 a0, a1;
    const bool more = (s + 1 < nsteps);
    if (more) {
      stage_b(cur ^ 1, (s + 1) * 32);        // async B into next buf
      load_a((s + 1) * 32, a0, a1);          // issue A loads (in flight over MFMA)
    }
    short8 af[4], bfv[4];
#pragma unroll
    for (int i = 0; i < 4; ++i) af[i]  = *(const short8*)&Ab[cur][i][l][0];
#pragma unroll
    for (int j = 0; j < 4; ++j) bfv[j] = *(const short8*)&Bb[cur][4 * w + j][l][0];
#pragma unroll
    for (int i = 0; i < 4; ++i)
#pragma unroll
      for (int j = 0; j < 4; ++j)
        acc[i][j] = __builtin_amdgcn_mfma_f32_16x16x32_bf16(
            as_bf8(af[i]), as_bf8(bfv[j]), acc[i][j], 0, 0, 0);
    if (more) write_a(cur ^ 1, a0, a1);      // convert + ds_write after MFMA
    __syncthreads();
  }

  float* outp = Out + (size_t)blockIdx.y * ((size_t)BB * SS * NHID);
  const int orow = m0 + ((l >> 4) << 2);
  const int ocol = (w << 6) + (l & 15);
#pragma unroll
  for (int i = 0; i < 4; ++i)
#pragma unroll
    for (int j = 0; j < 4; ++j) {
      const int row = orow + i * 16, col = ocol + j * 16;
#pragma unroll
      for (int r = 0; r < 4; ++r)
        outp[(size_t)(row + r) * NHID + col] = acc[i][j][r];
    }
}

// ---------------------------------------------------------------------------
// hp GEMM: hpT[b][d(256)][j(128)] bf16 = (h @ Wg)^T per batch.
//   BM=64, BN=128, BK=32; 256 thr = 4 waves, wave w = cols [32w, 32w+32).
//   grid (M/64, 2) = 512 blocks.
// ---------------------------------------------------------------------------
__global__ __launch_bounds__(256, 2) void k_gemm_hp(
    const unsigned short* __restrict__ A,   // [M][256] bf16 (h)
    const unsigned short* __restrict__ Bt,  // [256][256] bf16 (Wg^T)
    unsigned short* __restrict__ hpT)       // [BB][256][128] bf16
{
  __shared__ __align__(16) unsigned short Ab[2][4][64][8];   // 8 KB
  __shared__ __align__(16) unsigned short Bb[2][8][64][8];   // 16 KB
  const int tid = threadIdx.x, l = tid & 63, w = tid >> 6;
  const int m0 = blockIdx.x * 64, n0 = blockIdx.y * 128;

  const unsigned short* aB = A  + (size_t)(m0 + (l & 15)) * NHID + (l >> 4) * 8;
  const unsigned short* bB = Bt + (size_t)(n0 + (l & 15)) * NHID + (l >> 4) * 8;

  f32x4 acc[4][2];
#pragma unroll
  for (int i = 0; i < 4; ++i)
#pragma unroll
    for (int j = 0; j < 2; ++j) acc[i][j] = (f32x4)(0.f);

  auto stage = [&](int buf, int koff) {
#pragma unroll
    for (int q = 0; q < 3; ++q) {
      const int t = w * 3 + q;               // 0..11, wave-uniform
      if (t < 4) {
        GLOAD_LDS16(aB + (size_t)(16 * t) * NHID + koff, &Ab[buf][t][0][0]);
      } else {
        GLOAD_LDS16(bB + (size_t)(16 * (t - 4)) * NHID + koff, &Bb[buf][t - 4][0][0]);
      }
    }
  };

  stage(0, 0);
  __syncthreads();

  for (int s = 0; s < 8; ++s) {
    const int cur = s & 1;
    if (s + 1 < 8) stage(cur ^ 1, (s + 1) * 32);
    short8 af[4], bfv[2];
#pragma unroll
    for (int i = 0; i < 4; ++i) af[i]  = *(const short8*)&Ab[cur][i][l][0];
#pragma unroll
    for (int j = 0; j < 2; ++j) bfv[j] = *(const short8*)&Bb[cur][2 * w + j][l][0];
#pragma unroll
    for (int i = 0; i < 4; ++i)
#pragma unroll
      for (int j = 0; j < 2; ++j)
        acc[i][j] = __builtin_amdgcn_mfma_f32_16x16x32_bf16(
            as_bf8(af[i]), as_bf8(bfv[j]), acc[i][j], 0, 0, 0);
    __syncthreads();
  }

  // transposed store: hpT[b][col][row_in_batch]
  const int bidx = m0 >> 7;
  const int rb0  = (m0 & 127) + ((l >> 4) << 2);
  unsigned short* hb = hpT + (size_t)bidx * NHID * SS;
#pragma unroll
  for (int i = 0; i < 4; ++i)
#pragma unroll
    for (int j = 0; j < 2; ++j) {
      const int col = n0 + (2 * w + j) * 16 + (l & 15);
      bfs4 o;
#pragma unroll
      for (int r = 0; r < 4; ++r) o[r] = (short)f2bf(acc[i][j][r]);
      *(bfs4*)&hb[(size_t)col * SS + rb0 + i * 16] = o;
    }
}

// ---------------------------------------------------------------------------
// Fused: x = X0 (+X1) (+bias) -> LayerNorm -> GELU -> bf16 h (+f32 h)
//        (+ scores c1 = h@u1, c2 = h@u2 when u != null)
// ---------------------------------------------------------------------------
__global__ __launch_bounds__(256) void k_ln_fuse(
    const float* __restrict__ X0, const float* __restrict__ X1,
    const float* __restrict__ bias, const float* __restrict__ g,
    const float* __restrict__ b, unsigned short* __restrict__ out_bf,
    float* __restrict__ out_f32, const float* __restrict__ u,
    float* __restrict__ c1, float* __restrict__ c2)
{
  const int tid = threadIdx.x, l = tid & 63, w = tid >> 6;
  const f32x4 gg = *(const f32x4*)(g + l * 4);
  const f32x4 bb = *(const f32x4*)(b + l * 4);
  f32x4 bias4 = (f32x4)(0.f);
  if (bias) bias4 = *(const f32x4*)(bias + l * 4);
  f32x4 u1v[4], u2v[4];
  if (u) {
#pragma unroll
    for (int t = 0; t < 4; ++t) {
      u1v[t] = *(const f32x4*)(u + (size_t)(4 * l + t) * 4);
      u2v[t] = *(const f32x4*)(u + 1024 + (size_t)(4 * l + t) * 4);
    }
  }
  for (int it = 0; it < 4; ++it) {
    const int row = blockIdx.x * 16 + w * 4 + it;
    f32x4 x = *(const f32x4*)(X0 + (size_t)row * NHID + l * 4);
    if (X1) {
      f32x4 x1 = *(const f32x4*)(X1 + (size_t)row * NHID + l * 4);
      x.x += x1.x; x.y += x1.y; x.z += x1.z; x.w += x1.w;
    }
    x.x += bias4.x; x.y += bias4.y; x.z += bias4.z; x.w += bias4.w;
    float s  = x.x + x.y + x.z + x.w;
    float sq = x.x * x.x + x.y * x.y + x.z * x.z + x.w * x.w;
#pragma unroll
    for (int m = 1; m < 64; m <<= 1) { s += __shfl_xor(s, m); sq += __shfl_xor(sq, m); }
    const float mu   = s * (1.f / 256.f);
    const float var  = sq * (1.f / 256.f) - mu * mu;
    const float rstd = rsqrtf(var + 1e-5f);
    float y[4];
#pragma unroll
    for (int t = 0; t < 4; ++t) {
      float yy = (x[t] - mu) * rstd * gg[t] + bb[t];
      y[t] = 0.5f * yy * (1.f + erff(yy * 0.70710678118654752f));
    }
    if (out_bf) {
      bfs4 o;
#pragma unroll
      for (int t = 0; t < 4; ++t) o[t] = (short)f2bf(y[t]);
      *(bfs4*)(out_bf + (size_t)row * NHID + l * 4) = o;
    }
    if (out_f32) {
      f32x4 o; o.x = y[0]; o.y = y[1]; o.z = y[2]; o.w = y[3];
      *(f32x4*)(out_f32 + (size_t)row * NHID + l * 4) = o;
    }
    if (u) {
      float d1[4] = {0.f,0.f,0.f,0.f}, d2[4] = {0.f,0.f,0.f,0.f};
#pragma unroll
      for (int t = 0; t < 4; ++t)
#pragma unroll
        for (int h = 0; h < 4; ++h) {
          d1[h] += y[t] * u1v[t][h];
          d2[h] += y[t] * u2v[t][h];
        }
#pragma unroll
      for (int h = 0; h < 4; ++h) {
#pragma unroll
        for (int m = 1; m < 64; m <<= 1) {
          d1[h] += __shfl_xor(d1[h], m);
          d2[h] += __shfl_xor(d2[h], m);
        }
      }
      if (l == 0) {
#pragma unroll
        for (int h = 0; h < 4; ++h) {
          c1[(size_t)row * 4 + h] = d1[h];
          c2[(size_t)row * 4 + h] = d2[h];
        }
      }
    }
  }
}

// ---------------------------------------------------------------------------
// Fold a_src/a_dst/a_edge into u matrices (both layers; blockIdx.x = layer)
// ---------------------------------------------------------------------------
__global__ __launch_bounds__(256, 1) void k_proj(
    const float* __restrict__ Wg, const float* __restrict__ We,
    const float* __restrict__ asrc, const float* __restrict__ adst,
    const float* __restrict__ aedge, float* __restrict__ u)
{
  const int lyr = blockIdx.x;
  const int k = threadIdx.x;
  const float* Wgl = Wg + (size_t)lyr * NHID * NHID;
  const float* Wel = We + (size_t)lyr * NHID * NHID;
  float* u1 = u + (size_t)lyr * 2048;
  float* u2 = u1 + 1024;
#pragma unroll
  for (int h = 0; h < 4; ++h) {
    float ss = 0.f, sd = 0.f, se = 0.f;
    const float* wg  = Wgl + k * NHID + h * 64;
    const float* we  = Wel + k * NHID + h * 64;
    const float* pas = asrc + lyr * NHEAD * HDIM + h * 64;
    const float* pad_ = adst + lyr * NHEAD * HDIM + h * 64;
    const float* pae = aedge + lyr * NHEAD * HDIM + h * 64;
#pragma unroll 4
    for (int d = 0; d < 64; ++d) {
      ss += wg[d] * pas[d];
      sd += wg[d] * pad_[d];
      se += we[d] * pae[d];
    }
    u1[k * 4 + h] = ss + se;
    u2[k * 4 + h] = sd - se;
  }
}

// ---------------------------------------------------------------------------
// GAT attention: block per (head, b). Lane-per-row softmax, bitmask adj,
// Vb staged from transposed hp via global_load_lds, PV via MFMA.
// ---------------------------------------------------------------------------
__global__ __launch_bounds__(256) void k_attn2(
    const unsigned short* __restrict__ hpT, const float* __restrict__ c1,
    const float* __restrict__ c2, const unsigned long long* __restrict__ abits,
    float* __restrict__ out)
{
  __shared__ __align__(16) unsigned short Pb[4][8][64][8];   // 32 KB A-frags
  __shared__ __align__(16) unsigned short Vb[4][4][64][8];   // 16 KB B-frags
  __shared__ float s1[128], s2[128];
  __shared__ float mbuf[2][128], sbuf[2][128], invsum[128];
  const int head = blockIdx.x, b = blockIdx.y;
  const int tid = threadIdx.x, w = tid >> 6, l = tid & 63;

  if (tid < 128) {
    const int m = b * SS + tid;
    s1[tid] = c1[m * 4 + head];
    s2[tid] = c2[m * 4 + head];
  }
  // stage hpT slice -> Vb B-fragment layout (async, per-lane global addr)
  {
    const unsigned short* hb = hpT + ((size_t)b * NHID + head * 64) * SS;
#pragma unroll
    for (int q = 0; q < 4; ++q) {
      const int tile = w * 4 + q;                  // 0..15, wave-uniform
      const int kstep = tile >> 2, nt = tile & 3;
      const unsigned short* src =
          hb + (size_t)(nt * 16 + (l & 15)) * SS + kstep * 32 + (l >> 4) * 8;
      GLOAD_LDS16(src, &Vb[kstep][nt][0][0]);
    }
  }
  __syncthreads();

  const int i = tid & 127, half = tid >> 7;
  const float s1v = s1[i];
  const unsigned long long bits = abits[((size_t)b * SS + i) * 2 + half];

  // pass 1: row-half max (serial per thread, 4 independent chains)
  float ma[4] = {-3.0e38f, -3.0e38f, -3.0e38f, -3.0e38f};
#pragma unroll
  for (int jl = 0; jl < 64; ++jl) {
    float x  = s1v + s2[half * 64 + jl];
    float lk = fmaxf(x, 0.2f * x);                  // LeakyReLU(0.2)
    float xm = ((bits >> jl) & 1ull) ? lk : -3.0e38f;
    ma[jl & 3] = fmaxf(ma[jl & 3], xm);
  }
  mbuf[half][i] = fmaxf(fmaxf(ma[0], ma[1]), fmaxf(ma[2], ma[3]));
  __syncthreads();
  const float mrow = fmaxf(mbuf[0][i], mbuf[1][i]);

  // pass 2: exp, sum, write P fragments (unnormalized, bf16)
  float sa[4] = {0.f, 0.f, 0.f, 0.f};
#pragma unroll
  for (int grp = 0; grp < 8; ++grp) {
    short8 pv;
#pragma unroll
    for (int e = 0; e < 8; ++e) {
      const int jl = grp * 8 + e;
      float x  = s1v + s2[half * 64 + jl];
      float lk = fmaxf(x, 0.2f * x);
      float xm = ((bits >> jl) & 1ull) ? lk : -3.0e38f;
      float p  = exp2f((xm - mrow) * 1.4426950408889634f);
      sa[e & 3] += p;
      pv[e] = (short)f2bf(p);
    }
    const int j = half * 64 + grp * 8;
    const int kstep = j >> 5, g = (j >> 3) & 3;
    *(short8*)&Pb[kstep][i >> 4][(g << 4) | (i & 15)][0] = pv;
  }
  sbuf[half][i] = (sa[0] + sa[1]) + (sa[2] + sa[3]);
  __syncthreads();
  if (tid < 128) invsum[tid] = 1.f / (sbuf[0][tid] + sbuf[1][tid]);
  __syncthreads();

  // phase 3: PV via MFMA. wave w owns output rows [w*32, w*32+32)
  f32x4 acc[2][4];
#pragma unroll
  for (int ii = 0; ii < 2; ++ii)
#pragma unroll
    for (int nt = 0; nt < 4; ++nt) acc[ii][nt] = (f32x4)(0.f);
#pragma unroll
  for (int kstep = 0; kstep < 4; ++kstep) {
    short8 bv[4];
#pragma unroll
    for (int nt = 0; nt < 4; ++nt) bv[nt] = *(const short8*)&Vb[kstep][nt][l][0];
#pragma unroll
    for (int ii = 0; ii < 2; ++ii) {
      short8 af = *(const short8*)&Pb[kstep][2 * w + ii][l][0];
#pragma unroll
      for (int nt = 0; nt < 4; ++nt)
        acc[ii][nt] = __builtin_amdgcn_mfma_f32_16x16x32_bf16(
            as_bf8(af), as_bf8(bv[nt]), acc[ii][nt], 0, 0, 0);
    }
  }

  // epilogue: normalize by 1/sum and store f32
  float* ob = out + (size_t)(b * SS) * NHID + head * 64;
#pragma unroll
  for (int ii = 0; ii < 2; ++ii) {
    const int it = 2 * w + ii;
#pragma unroll
    for (int r = 0; r < 4; ++r) {
      const int row = it * 16 + (l >> 4) * 4 + r;
      const float inv = invsum[row];
#pragma unroll
      for (int nt = 0; nt < 4; ++nt)
        ob[(size_t)row * NHID + nt * 16 + (l & 15)] = acc[ii][nt][r] * inv;
    }
  }
}

// ---------------------------------------------------------------------------
// Final projection: Z[16384 x 64] = h @ Wz + bz.  64 rows per block.
// ---------------------------------------------------------------------------
__global__ __launch_bounds__(256, 1) void k_zgemm(
    const float* __restrict__ hmat, const float* __restrict__ Wz,
    const float* __restrict__ bz, float* __restrict__ Z)
{
  __shared__ __align__(16) float hrows[64 * 256];
  const int tid = threadIdx.x, w = tid >> 6, l = tid & 63;
  const int r0 = blockIdx.x * 64;
  const f32x4* src = (const f32x4*)(hmat + (size_t)r0 * NHID);
#pragma unroll
  for (int rep = 0; rep < 16; ++rep)
    ((f32x4*)hrows)[rep * 256 + tid] = src[rep * 256 + tid];
  __syncthreads();
  const float bzv = bz[l];
  const int rbase = w * 16;
#pragma unroll
  for (int pass = 0; pass < 4; ++pass) {
    float acc0 = 0.f, acc1 = 0.f, acc2 = 0.f, acc3 = 0.f;
    const float* h0 = &hrows[(rbase + pass * 4) * 256];
#pragma unroll 8
    for (int k = 0; k < 256; ++k) {
      float wv = Wz[k * 64 + l];
      acc0 += h0[k] * wv;
      acc1 += h0[256 + k] * wv;
      acc2 += h0[512 + k] * wv;
      acc3 += h0[768 + k] * wv;
    }
    float* zp = Z + (size_t)(r0 + rbase + pass * 4) * 64 + l;
    zp[0]   = acc0 + bzv;
    zp[64]  = acc1 + bzv;
    zp[128] = acc2 + bzv;
    zp[192] = acc3 + bzv;
  }
}

// ---------------------------------------------------------------------------
extern "C" void kernel_launch(void* const* d_in, const int* in_sizes, int n_in,
                              void* d_out, int out_size, void* d_ws, size_t ws_size,
                              hipStream_t stream)
{
  const float* x_set   = (const float*)d_in[0];
  const int*   adj     = (const int*)d_in[1];
  const float* W_in    = (const float*)d_in[2];
  const float* b_in    = (const float*)d_in[3];
  const float* ln_in_g = (const float*)d_in[4];
  const float* ln_in_b = (const float*)d_in[5];
  const float* Wg      = (const float*)d_in[6];
  const float* a_src   = (const float*)d_in[7];
  const float* a_dst   = (const float*)d_in[8];
  const float* a_edge  = (const float*)d_in[9];
  const float* We      = (const float*)d_in[10];
  const float* ln_g    = (const float*)d_in[11];
  const float* ln_b    = (const float*)d_in[12];
  const float* Wz      = (const float*)d_in[13];
  const float* bz      = (const float*)d_in[14];
  float* zout = (float*)d_out;

  const int M = BB * SS;   // 16384

  char* base = (char*)d_ws;
  size_t off = 0;
  auto alloc = [&](size_t bytes) { char* p = base + off; off += (bytes + 255) & ~(size_t)255; return p; };
  float*          P     = (float*)alloc((size_t)M * NHID * 4 * 2);           // 33.6 MB (P0,P1)
  unsigned short* hbf   = (unsigned short*)alloc((size_t)M * NHID * 2);      // 8.4 MB
  unsigned short* hpT   = (unsigned short*)alloc((size_t)M * NHID * 2);      // 8.4 MB
  float*          bufA  = (float*)alloc((size_t)M * NHID * 4);               // 16.8 MB
  unsigned short* wt_in = (unsigned short*)alloc((size_t)NHID * KPAD * 2);   // 1 MB
  unsigned short* wgt   = (unsigned short*)alloc((size_t)NHID * NHID * 2);   // 128 KB
  float*          u     = (float*)alloc(2 * 2048 * 4);
  float*          c1    = (float*)alloc((size_t)M * 4 * 4);
  float*          c2    = (float*)alloc((size_t)M * 4 * 4);
  unsigned long long* abits = (unsigned long long*)alloc((size_t)BB * SS * 2 * 8); // 256 KB
  float* hfin = P;                                 // final h f32 (reuse P0)

  // 1) W_in -> bf16 transposed+padded
  k_transconv<<<dim3((NHID * KPAD) / 256), dim3(256), 0, stream>>>(
      W_in, wt_in, GG, NHID, KPAD);
  // 2) fold attention vectors (both layers); pack adj bitmask
  k_proj<<<dim3(2), dim3(256), 0, stream>>>(Wg, We, a_src, a_dst, a_edge, u);
  k_adjpack<<<dim3(BB * SS * 2 / 4), dim3(256), 0, stream>>>(adj, abits);
  // 3) input proj GEMM (fused f32->bf16 A), split-K=2 -> P0,P1
  k_gemm_in<<<dim3(M / 64, 2), dim3(256), 0, stream>>>(x_set, wt_in, P);
  // 4) reduce + bias + LN + GELU -> hbf, + scores for layer 0
  k_ln_fuse<<<dim3(M / 16), dim3(256), 0, stream>>>(
      P, P + (size_t)M * NHID, b_in, ln_in_g, ln_in_b, hbf, nullptr,
      u, c1, c2);

  for (int l = 0; l < 2; ++l) {
    const float* Wgl = Wg + (size_t)l * NHID * NHID;
    // a) Wg[l] -> bf16 transposed
    k_transconv<<<dim3((NHID * NHID) / 256), dim3(256), 0, stream>>>(
        Wgl, wgt, NHID, NHID, NHID);
    // b) hp^T = (h @ Wg[l])^T -> hpT (bf16)
    k_gemm_hp<<<dim3(M / 64, 2), dim3(256), 0, stream>>>(hbf, wgt, hpT);
    // c) attention -> bufA
    k_attn2<<<dim3(NHEAD, BB), dim3(256), 0, stream>>>(
        hpT, c1, c2, abits, bufA);
    // d) LN + GELU (+ next-layer scores, or final f32 h)
    if (l == 0) {
      k_ln_fuse<<<dim3(M / 16), dim3(256), 0, stream>>>(
          bufA, nullptr, nullptr, ln_g, ln_b, hbf, nullptr,
          u + 2048, c1, c2);
    } else {
      k_ln_fuse<<<dim3(M / 16), dim3(256), 0, stream>>>(
          bufA, nullptr, nullptr, ln_g + NHID, ln_b + NHID, nullptr, hfin,
          nullptr, nullptr, nullptr);
    }
  }

  // 6) final projection
  k_zgemm<<<dim3(M / 64), dim3(256), 0, stream>>>(hfin, Wz, bz, zout);
}